// Round 1
// baseline (558.845 us; speedup 1.0000x reference)
//
#include <hip/hip_runtime.h>
#include <math.h>

#define HDIM  1024
#define HHALF 512
#define NEXP  8
#define NTOK  4096
#define CAP   1536
#define TOTAL_DC (2u * NTOK * NEXP * CAP)   // 100,663,296 floats (dispatch+combine)
#define TK_FLOATS 16384                     // 8192 int experts + 8192 float probs

// ---------------------------------------------------------------------------
// GEMM: Hout[M,N] = relu(A[M,K] @ B[K,N] + bias[N]),  M=4096, K=1024 fixed.
// 128x128 tile, BK=16, 256 threads, 8x8 per thread, fp32.
// ---------------------------------------------------------------------------
__global__ __launch_bounds__(256) void gemm_bias_relu(
    const float* __restrict__ A, const float* __restrict__ B,
    const float* __restrict__ bias, float* __restrict__ Hout, int N)
{
    __shared__ float As[16][132];   // transposed: As[k][row]
    __shared__ float Bs[16][132];   // Bs[k][col]

    const int tid = threadIdx.x;
    const int tx = tid & 15, ty = tid >> 4;
    const int rowBase = blockIdx.y * 128;
    const int colBase = blockIdx.x * 128;

    const int lrow = tid >> 1;          // 0..127
    const int lkq  = (tid & 1) * 8;     // 0 or 8
    const int bkk  = tid >> 4;          // 0..15
    const int bcol = (tid & 15) * 8;    // 0..120

    float acc[8][8];
#pragma unroll
    for (int i = 0; i < 8; i++)
#pragma unroll
        for (int j = 0; j < 8; j++) acc[i][j] = 0.f;

    const float* Aptr = A + (size_t)(rowBase + lrow) * HDIM + lkq;
    const float* Bptr = B + (size_t)bkk * N + colBase + bcol;

    for (int k0 = 0; k0 < HDIM; k0 += 16) {
        float4 a0 = *(const float4*)(Aptr + k0);
        float4 a1 = *(const float4*)(Aptr + k0 + 4);
        float4 b0 = *(const float4*)(Bptr + (size_t)k0 * N);
        float4 b1 = *(const float4*)(Bptr + (size_t)k0 * N + 4);
        __syncthreads();   // previous compute done before overwrite
        As[lkq + 0][lrow] = a0.x;
        As[lkq + 1][lrow] = a0.y;
        As[lkq + 2][lrow] = a0.z;
        As[lkq + 3][lrow] = a0.w;
        As[lkq + 4][lrow] = a1.x;
        As[lkq + 5][lrow] = a1.y;
        As[lkq + 6][lrow] = a1.z;
        As[lkq + 7][lrow] = a1.w;
        *(float4*)&Bs[bkk][bcol]     = b0;
        *(float4*)&Bs[bkk][bcol + 4] = b1;
        __syncthreads();
#pragma unroll
        for (int kk = 0; kk < 16; kk++) {
            float4 x0 = *(const float4*)&As[kk][ty * 8];
            float4 x1 = *(const float4*)&As[kk][ty * 8 + 4];
            float4 y0 = *(const float4*)&Bs[kk][tx * 8];
            float4 y1 = *(const float4*)&Bs[kk][tx * 8 + 4];
            float av[8] = {x0.x, x0.y, x0.z, x0.w, x1.x, x1.y, x1.z, x1.w};
            float bv[8] = {y0.x, y0.y, y0.z, y0.w, y1.x, y1.y, y1.z, y1.w};
#pragma unroll
            for (int i = 0; i < 8; i++)
#pragma unroll
                for (int j = 0; j < 8; j++)
                    acc[i][j] = fmaf(av[i], bv[j], acc[i][j]);
        }
    }

#pragma unroll
    for (int i = 0; i < 8; i++) {
        const int r = rowBase + ty * 8 + i;
        const int c = colBase + tx * 8;
#pragma unroll
        for (int j = 0; j < 8; j += 4) {
            float4 v;
            v.x = fmaxf(acc[i][j + 0] + bias[c + j + 0], 0.f);
            v.y = fmaxf(acc[i][j + 1] + bias[c + j + 1], 0.f);
            v.z = fmaxf(acc[i][j + 2] + bias[c + j + 2], 0.f);
            v.w = fmaxf(acc[i][j + 3] + bias[c + j + 3], 0.f);
            *(float4*)&Hout[(size_t)r * N + c + j] = v;
        }
    }
}

// ---------------------------------------------------------------------------
// Per-token second layer: importance logit, router logits, softmax, top-2.
// One block (256 thr) per token.
// ---------------------------------------------------------------------------
__global__ __launch_bounds__(256) void second_layer(
    const float* __restrict__ h_i, const float* __restrict__ h_r,
    const float* __restrict__ h_u,
    const float* __restrict__ wi2, const float* __restrict__ bi2,
    const float* __restrict__ wr2, const float* __restrict__ br2,
    const float* __restrict__ wu2, const float* __restrict__ bu2,
    float* __restrict__ oprobs, float* __restrict__ oimp,
    int* __restrict__ tke, float* __restrict__ tkp)
{
    const int t = blockIdx.x;
    const int tid = threadIdx.x;

    float pi = 0.f;
    float pr[8], pu[8];
#pragma unroll
    for (int e = 0; e < 8; e++) { pr[e] = 0.f; pu[e] = 0.f; }

    const float* hi = h_i + (size_t)t * HHALF;
    const float* hr = h_r + (size_t)t * HDIM;
    const float* hu = h_u + (size_t)t * HDIM;

    for (int j = tid; j < HHALF; j += 256) pi = fmaf(hi[j], wi2[j], pi);
    for (int j = tid; j < HDIM; j += 256) {
        float a = hr[j], b = hu[j];
#pragma unroll
        for (int e = 0; e < 8; e++) {
            pr[e] = fmaf(a, wr2[j * 8 + e], pr[e]);
            pu[e] = fmaf(b, wu2[j * 8 + e], pu[e]);
        }
    }

#pragma unroll
    for (int off = 32; off > 0; off >>= 1) {
        pi += __shfl_down(pi, off, 64);
#pragma unroll
        for (int e = 0; e < 8; e++) {
            pr[e] += __shfl_down(pr[e], off, 64);
            pu[e] += __shfl_down(pu[e], off, 64);
        }
    }

    __shared__ float red[4][17];
    const int lane = tid & 63, wv = tid >> 6;
    if (lane == 0) {
        red[wv][0] = pi;
#pragma unroll
        for (int e = 0; e < 8; e++) { red[wv][1 + e] = pr[e]; red[wv][9 + e] = pu[e]; }
    }
    __syncthreads();

    if (tid == 0) {
        float si = red[0][0] + red[1][0] + red[2][0] + red[3][0] + bi2[0];
        float sig = 1.f / (1.f + expf(-si));
        oimp[t] = sig;
        const bool m = sig > 0.5f;
        float lg[8];
#pragma unroll
        for (int e = 0; e < 8; e++) {
            float vr = red[0][1 + e] + red[1][1 + e] + red[2][1 + e] + red[3][1 + e] + br2[e];
            float vu = red[0][9 + e] + red[1][9 + e] + red[2][9 + e] + red[3][9 + e] + bu2[e];
            lg[e] = m ? vr : vu;
        }
        float mx = lg[0];
#pragma unroll
        for (int e = 1; e < 8; e++) mx = fmaxf(mx, lg[e]);
        float p[8], s = 0.f;
#pragma unroll
        for (int e = 0; e < 8; e++) { p[e] = expf(lg[e] - mx); s += p[e]; }
        const float inv = 1.f / s;
#pragma unroll
        for (int e = 0; e < 8; e++) { p[e] *= inv; oprobs[t * 8 + e] = p[e]; }
        // top-2, ties -> lowest index (matches stable descending sort)
        int i1 = 0;
#pragma unroll
        for (int e = 1; e < 8; e++) if (p[e] > p[i1]) i1 = e;
        int i2 = (i1 == 0) ? 1 : 0;
#pragma unroll
        for (int e = 0; e < 8; e++) if (e != i1 && p[e] > p[i2]) i2 = e;
        const float ps = p[i1] + p[i2];
        tke[t]        = i1;
        tke[NTOK + t] = i2;
        tkp[t]        = p[i1] / ps;
        tkp[NTOK + t] = p[i2] / ps;
    }
}

// ---------------------------------------------------------------------------
// Aux loss: deterministic single-block reduction over probs + mask.
// ---------------------------------------------------------------------------
__global__ __launch_bounds__(256) void aux_kernel(
    const float* __restrict__ oprobs, const float* __restrict__ oimp,
    float* __restrict__ oaux)
{
    const int tid = threadIdx.x;
    float ap[8], ai[8];
#pragma unroll
    for (int e = 0; e < 8; e++) { ap[e] = 0.f; ai[e] = 0.f; }

    for (int t = tid; t < NTOK; t += 256) {
        const float msk = (oimp[t] > 0.5f) ? 1.f : 0.f;
#pragma unroll
        for (int e = 0; e < 8; e++) {
            float p = oprobs[t * 8 + e];
            ap[e] += p;
            ai[e] = fmaf(msk, p, ai[e]);
        }
    }
#pragma unroll
    for (int off = 32; off > 0; off >>= 1) {
#pragma unroll
        for (int e = 0; e < 8; e++) {
            ap[e] += __shfl_down(ap[e], off, 64);
            ai[e] += __shfl_down(ai[e], off, 64);
        }
    }
    __shared__ float red[4][16];
    const int lane = tid & 63, wv = tid >> 6;
    if (lane == 0) {
#pragma unroll
        for (int e = 0; e < 8; e++) { red[wv][e] = ap[e]; red[wv][8 + e] = ai[e]; }
    }
    __syncthreads();
    if (tid == 0) {
        float ent = 0.f, tot = 0.f, isv[8];
#pragma unroll
        for (int e = 0; e < 8; e++) {
            float sp = red[0][e] + red[1][e] + red[2][e] + red[3][e];
            float sm = red[0][8 + e] + red[1][8 + e] + red[2][8 + e] + red[3][8 + e];
            float r = sp / (float)NTOK;
            ent += r * logf(r * 8.f + 1e-9f);
            isv[e] = sm + 1e-9f;
            tot += isv[e];
        }
        float ie = 0.f;
#pragma unroll
        for (int e = 0; e < 8; e++) {
            float q = isv[e] / tot;
            ie -= q * logf(q + 1e-9f);
        }
        oaux[0] = ent - 0.1f * (ie / logf(8.f));
    }
}

// ---------------------------------------------------------------------------
// Scan + scatter. Single block. Top-k data lives in the 64 KB tail of the
// combine region (memset spares it); copied to LDS, tail zeroed, then k-major
// per-expert running positions computed and nonzeros scattered.
// ---------------------------------------------------------------------------
__global__ __launch_bounds__(256) void scan_scatter(float* __restrict__ out)
{
    __shared__ unsigned char se[2 * NTOK];   // 8 KB expert ids
    __shared__ float         sp[2 * NTOK];   // 32 KB gate probs
    __shared__ int cnts[256][8];             // 8 KB

    const int tid = threadIdx.x;
    float* tail = out + ((size_t)TOTAL_DC - TK_FLOATS);
    const int*   tke = (const int*)tail;
    const float* tkp = (const float*)(tail + 2 * NTOK);

    for (int i = tid; i < 2 * NTOK; i += 256) {
        se[i] = (unsigned char)tke[i];
        sp[i] = tkp[i];
    }
    __syncthreads();

    // zero the tail the memset skipped
    for (int i = tid; i < TK_FLOATS; i += 256) tail[i] = 0.f;

    // local per-expert counts over 32 consecutive k-major entries
    const int base = tid * 32;
    int c[8];
#pragma unroll
    for (int e = 0; e < 8; e++) c[e] = 0;
    for (int i = 0; i < 32; i++) {
        int e = se[base + i];
#pragma unroll
        for (int k = 0; k < 8; k++) c[k] += (e == k) ? 1 : 0;
    }
#pragma unroll
    for (int e = 0; e < 8; e++) cnts[tid][e] = c[e];
    __syncthreads();

    // exclusive scan over threads (8 experts, serial per expert)
    if (tid < 8) {
        int run = 0;
        for (int i = 0; i < 256; i++) {
            int v = cnts[i][tid];
            cnts[i][tid] = run;
            run += v;
        }
    }
    __syncthreads();

    int basecnt[8];
#pragma unroll
    for (int e = 0; e < 8; e++) basecnt[e] = cnts[tid][e];

    float* disp = out;
    float* comb = out + (size_t)NTOK * NEXP * CAP;

    for (int i = 0; i < 32; i++) {
        const int idx = base + i;
        const int e = se[idx];
        int pos = 0;
#pragma unroll
        for (int k = 0; k < 8; k++)
            if (e == k) { pos = basecnt[k]; basecnt[k]++; }
        if (pos < CAP) {
            const int tok = idx & (NTOK - 1);
            const size_t o = ((size_t)tok * NEXP + e) * CAP + pos;
            disp[o] = 1.0f;
            comb[o] = sp[idx];
        }
    }
}

// ---------------------------------------------------------------------------
extern "C" void kernel_launch(void* const* d_in, const int* in_sizes, int n_in,
                              void* d_out, int out_size, void* d_ws, size_t ws_size,
                              hipStream_t stream) {
    const float* x   = (const float*)d_in[0];
    const float* wi1 = (const float*)d_in[1];
    const float* bi1 = (const float*)d_in[2];
    const float* wi2 = (const float*)d_in[3];
    const float* bi2 = (const float*)d_in[4];
    const float* wr1 = (const float*)d_in[5];
    const float* br1 = (const float*)d_in[6];
    const float* wr2 = (const float*)d_in[7];
    const float* br2 = (const float*)d_in[8];
    const float* wu1 = (const float*)d_in[9];
    const float* bu1 = (const float*)d_in[10];
    const float* wu2 = (const float*)d_in[11];
    const float* bu2 = (const float*)d_in[12];

    float* out    = (float*)d_out;
    float* disp   = out;
    float* comb   = out + (size_t)NTOK * NEXP * CAP;
    float* oprobs = out + (size_t)TOTAL_DC;
    float* oaux   = oprobs + NTOK * NEXP;
    float* oimp   = oaux + 1;

    // scratch: activations live in the dispatch region (wiped by memset later)
    float* h_i = disp;                                // 4096*512
    float* h_r = h_i + (size_t)NTOK * HHALF;          // 4096*1024
    float* h_u = h_r + (size_t)NTOK * HDIM;           // 4096*1024 (ends at 10.5M)

    // top-k storage: last 64 KB of combine region (spared by the memset)
    float* tail = out + ((size_t)TOTAL_DC - TK_FLOATS);
    int*   tke  = (int*)tail;
    float* tkp  = tail + 2 * NTOK;

    dim3 blk(256);
    gemm_bias_relu<<<dim3(HHALF / 128, NTOK / 128), blk, 0, stream>>>(x, wi1, bi1, h_i, HHALF);
    gemm_bias_relu<<<dim3(HDIM / 128, NTOK / 128), blk, 0, stream>>>(x, wr1, br1, h_r, HDIM);
    gemm_bias_relu<<<dim3(HDIM / 128, NTOK / 128), blk, 0, stream>>>(x, wu1, bu1, h_u, HDIM);

    second_layer<<<NTOK, blk, 0, stream>>>(h_i, h_r, h_u, wi2, bi2, wr2, br2,
                                           wu2, bu2, oprobs, oimp, tke, tkp);
    aux_kernel<<<1, blk, 0, stream>>>(oprobs, oimp, oaux);

    // zero dispatch+combine except the top-k tail
    hipMemsetAsync(disp, 0, ((size_t)TOTAL_DC - TK_FLOATS) * sizeof(float), stream);

    scan_scatter<<<1, blk, 0, stream>>>(out);
}